// Round 7
// baseline (344.875 us; speedup 1.0000x reference)
//
#include <hip/hip_runtime.h>

// AttentionHead  B=4, T=2048, C=1024, HEAD=2048, fp32 in/out.
// Round 10 (base r9=335us):
//  (a) gemm_sv S-blocks XCD-grouped: xcd=l&7 owns half of one batch's
//      triangle -> Q/K panel reuse in that XCD's L2 (FETCH was 2.6x ideal).
//  (b) gemm_o256 split-K for tm>=4 (two chunks, fp32 atomicAdd: exactly 2
//      commutative contributors -> bitwise deterministic). O rows>=1024
//      zeroed by softmax blocks (each owns its row; zero after read).
//      Slot table longest-first: makespan ~11 iter-units vs 16.
//  (c) cast_x+wcast_t+bias_cat fused into prep (8->5 launches).

#define T_    2048
#define C_    1024
#define B_    4
#define NQK   4096
#define SCALE 0.03125f   // C^-0.5 = 1/32 exactly

typedef __attribute__((ext_vector_type(4))) float floatx4;
typedef __attribute__((ext_vector_type(8))) short short8;
typedef __attribute__((ext_vector_type(8))) unsigned short ushortx8;

__device__ __forceinline__ unsigned short f2bf(float f) {
  unsigned int u = __float_as_uint(f);
  unsigned int r = (u + 0x7fffu + ((u >> 16) & 1u)) >> 16;  // RNE
  return (unsigned short)r;
}

// ------------------------- prep: cast x | cast+transpose W | bias concat
__global__ void prep_kernel(const float* __restrict__ x, ushort* __restrict__ xbf,
                            const float* __restrict__ Wq, const float* __restrict__ Wk,
                            const float* __restrict__ Wv, ushort* __restrict__ WtT,
                            const float* __restrict__ bq, const float* __restrict__ bk,
                            const float* __restrict__ bv, float* __restrict__ bcat) {
  int bx = blockIdx.x, tid = threadIdx.x;
  if (bx < 8192) {                                  // cast x (float4 per thread)
    int i = bx * 256 + tid;
    float4 v = ((const float4*)x)[i];
    ushort4 o;
    o.x = f2bf(v.x); o.y = f2bf(v.y); o.z = f2bf(v.z); o.w = f2bf(v.w);
    ((ushort4*)xbf)[i] = o;
  } else if (bx < 8192 + 6144) {                    // W cast+transpose, 32x32 tile
    int w = bx - 8192;
    int k0 = (w & 31) * 32, n0 = (w >> 5) * 32;
    const float* W = (n0 < 2048) ? Wq : (n0 < 4096 ? Wk : Wv);
    int nl0 = n0 & 2047;
    __shared__ ushort tile[32][33];
    int tx = tid & 31, ty = tid >> 5;
    for (int r = ty; r < 32; r += 8)
      tile[r][tx] = f2bf(W[(size_t)(k0 + r) * 2048 + nl0 + tx]);
    __syncthreads();
    for (int r = ty; r < 32; r += 8)
      WtT[(size_t)(n0 + r) * 1024 + k0 + tx] = tile[tx][r];
  } else {                                          // bias concat
    int i = (bx - 14336) * 256 + tid;
    if (i < 6144) {
      const float* s = (i < 2048) ? bq : (i < 4096 ? bk : bv);
      bcat[i] = s[i & 2047];
    }
  }
}

// ===================== 256x256 pair-pipelined GEMM core (BT, bf16) ==============
// Geometry: BM=BN=256, BK=64, 8 waves (wm=wave>>2, wn=wave&3), per-wave output
// 128x64 (acc[8][4] of 16x16 frags). LDS 128 KiB:
//   A: buf0 @0,16384; buf1 @32768,49152   (region = 128 rows x 64 cols bf16)
//   B: buf0 @65536,81920; buf1 @98304,114688
// Swizzle: physical byte-in-row = logical ^ ((row&7)<<4) (conflict-free, r5).
// Pair schedule per iter (tiles t=buf0, t+1=buf1), one s_barrier per pair:
//   pairA: read A-lo(t)+B(all,t), stage (t+1,A)->buf1A,  32 MFMA (m-lo)
//   pairB: read A-hi(t),          stage (t+2,B)->buf0B,  32 MFMA (m-hi)
//          gate vmcnt(4) [buf1A + prev buf1B confirmed]
//   pairC: read A-lo(t+1)+B(t+1), stage (t+2,A)->buf0A,  32 MFMA (m-lo)
//   pairD: read A-hi(t+1),        stage (t+3,B)->buf1B,  32 MFMA (m-hi)
//          gate vmcnt(4) [all buf0 for next iter confirmed]

#define MFMA16(a, b, c) __builtin_amdgcn_mfma_f32_16x16x32_bf16((a), (b), (c), 0, 0, 0)

#define GLDS16(gsrc, ldst)                                                                       \
  __builtin_amdgcn_global_load_lds((const __attribute__((address_space(1))) unsigned int*)(gsrc), \
                                   (__attribute__((address_space(3))) unsigned int*)(ldst), 16, 0, 0)

template <int LD>
__device__ __forceinline__ void stage_half(const ushort* gsrc, char* ldst) {
  GLDS16(gsrc, ldst);
  GLDS16(gsrc + 8 * LD, ldst + 1024);
}

#define BARX() do {                                        \
  __builtin_amdgcn_sched_barrier(0);                       \
  __builtin_amdgcn_s_barrier();                            \
  __builtin_amdgcn_sched_barrier(0);                       \
} while (0)

template <int LDA, int LDB>
__device__ __forceinline__ void prologue256(const ushort* Ap, const ushort* Bp,
                                            char* lds, int wave, int srcOffA, int srcOffB) {
  stage_half<LDA>(Ap + srcOffA,                     lds + wave * 2048);
  stage_half<LDA>(Ap + 128 * LDA + srcOffA,         lds + 16384 + wave * 2048);
  stage_half<LDB>(Bp + srcOffB,                     lds + 65536 + wave * 2048);
  stage_half<LDB>(Bp + 128 * LDB + srcOffB,         lds + 81920 + wave * 2048);
  stage_half<LDB>(Bp + 64 + srcOffB,                lds + 98304 + wave * 2048);
  stage_half<LDB>(Bp + 64 + 128 * LDB + srcOffB,    lds + 114688 + wave * 2048);
  __builtin_amdgcn_sched_barrier(0);
  asm volatile("s_waitcnt vmcnt(4)" ::: "memory");
  BARX();
}

template <int LDA, int LDB, bool TAIL>
__device__ __forceinline__ void iter256(const ushort* __restrict__ Ap,
                                        const ushort* __restrict__ Bp,
                                        char* lds, int kt0, int wave, int wm, int wn,
                                        int srcOffA, int srcOffB, int lnoff0,
                                        floatx4 (&acc)[8][4]) {
  char* rA0 = lds + wm * 16384;                    // tile kt0   (buf0) A, this wave
  char* rA1 = rA0 + 32768;                         // tile kt0+1 (buf1) A
  char* rB0 = lds + 65536 + (wn >> 1) * 16384 + (wn & 1) * 8192;
  char* rB1 = rB0 + 32768;
  const ushort* sA1 = Ap + (kt0 + 1) * 64 + srcOffA;
  const ushort* sA2 = Ap + (kt0 + 2) * 64 + srcOffA;
  const ushort* sB2 = Bp + (kt0 + 2) * 64 + srcOffB;
  const ushort* sB3 = Bp + (kt0 + 3) * 64 + srcOffB;
  const int lnoff1 = lnoff0 ^ 64;                  // second k-frag (swz carries bit6)
  short8 af[4][2], b4[4][2];

  // ==== pair A: tile kt0, m-lo rows x all n ============================
#pragma unroll
  for (int mi = 0; mi < 4; ++mi) {
    af[mi][0] = *(const short8*)(rA0 + mi * 2048 + lnoff0);
    af[mi][1] = *(const short8*)(rA0 + mi * 2048 + lnoff1);
  }
#pragma unroll
  for (int nj = 0; nj < 4; ++nj) {
    b4[nj][0] = *(const short8*)(rB0 + nj * 2048 + lnoff0);
    b4[nj][1] = *(const short8*)(rB0 + nj * 2048 + lnoff1);
  }
  stage_half<LDA>(sA1, lds + 32768 + wave * 2048);
  stage_half<LDA>(sA1 + 128 * LDA, lds + 49152 + wave * 2048);
  __builtin_amdgcn_s_setprio(1);
#pragma unroll
  for (int mi = 0; mi < 4; ++mi)
#pragma unroll
    for (int nj = 0; nj < 4; ++nj) {
      acc[mi][nj] = MFMA16(af[mi][0], b4[nj][0], acc[mi][nj]);
      acc[mi][nj] = MFMA16(af[mi][1], b4[nj][1], acc[mi][nj]);
    }
  __builtin_amdgcn_s_setprio(0);
  BARX();

  // ==== pair B: tile kt0, m-hi rows ====================================
#pragma unroll
  for (int mi = 0; mi < 4; ++mi) {
    af[mi][0] = *(const short8*)(rA0 + (4 + mi) * 2048 + lnoff0);
    af[mi][1] = *(const short8*)(rA0 + (4 + mi) * 2048 + lnoff1);
  }
  if constexpr (!TAIL) {
    stage_half<LDB>(sB2, lds + 65536 + wave * 2048);
    stage_half<LDB>(sB2 + 128 * LDB, lds + 81920 + wave * 2048);
  }
  __builtin_amdgcn_s_setprio(1);
#pragma unroll
  for (int mi = 0; mi < 4; ++mi)
#pragma unroll
    for (int nj = 0; nj < 4; ++nj) {
      acc[4 + mi][nj] = MFMA16(af[mi][0], b4[nj][0], acc[4 + mi][nj]);
      acc[4 + mi][nj] = MFMA16(af[mi][1], b4[nj][1], acc[4 + mi][nj]);
    }
  __builtin_amdgcn_s_setprio(0);
  __builtin_amdgcn_sched_barrier(0);
  if constexpr (TAIL) asm volatile("s_waitcnt vmcnt(0)" ::: "memory");
  else                asm volatile("s_waitcnt vmcnt(4)" ::: "memory");
  BARX();

  // ==== pair C: tile kt0+1, m-lo rows x all n ==========================
#pragma unroll
  for (int mi = 0; mi < 4; ++mi) {
    af[mi][0] = *(const short8*)(rA1 + mi * 2048 + lnoff0);
    af[mi][1] = *(const short8*)(rA1 + mi * 2048 + lnoff1);
  }
#pragma unroll
  for (int nj = 0; nj < 4; ++nj) {
    b4[nj][0] = *(const short8*)(rB1 + nj * 2048 + lnoff0);
    b4[nj][1] = *(const short8*)(rB1 + nj * 2048 + lnoff1);
  }
  if constexpr (!TAIL) {
    stage_half<LDA>(sA2, lds + wave * 2048);
    stage_half<LDA>(sA2 + 128 * LDA, lds + 16384 + wave * 2048);
  }
  __builtin_amdgcn_s_setprio(1);
#pragma unroll
  for (int mi = 0; mi < 4; ++mi)
#pragma unroll
    for (int nj = 0; nj < 4; ++nj) {
      acc[mi][nj] = MFMA16(af[mi][0], b4[nj][0], acc[mi][nj]);
      acc[mi][nj] = MFMA16(af[mi][1], b4[nj][1], acc[mi][nj]);
    }
  __builtin_amdgcn_s_setprio(0);
  BARX();

  // ==== pair D: tile kt0+1, m-hi rows ==================================
#pragma unroll
  for (int mi = 0; mi < 4; ++mi) {
    af[mi][0] = *(const short8*)(rA1 + (4 + mi) * 2048 + lnoff0);
    af[mi][1] = *(const short8*)(rA1 + (4 + mi) * 2048 + lnoff1);
  }
  if constexpr (!TAIL) {
    stage_half<LDB>(sB3, lds + 98304 + wave * 2048);
    stage_half<LDB>(sB3 + 128 * LDB, lds + 114688 + wave * 2048);
  }
  __builtin_amdgcn_s_setprio(1);
#pragma unroll
  for (int mi = 0; mi < 4; ++mi)
#pragma unroll
    for (int nj = 0; nj < 4; ++nj) {
      acc[4 + mi][nj] = MFMA16(af[mi][0], b4[nj][0], acc[4 + mi][nj]);
      acc[4 + mi][nj] = MFMA16(af[mi][1], b4[nj][1], acc[4 + mi][nj]);
    }
  __builtin_amdgcn_s_setprio(0);
  __builtin_amdgcn_sched_barrier(0);
  if constexpr (!TAIL) asm volatile("s_waitcnt vmcnt(4)" ::: "memory");
  BARX();
}

// Per-thread addressing for the 256x256 core.
struct Addr256 {
  int wave, wm, wn, ln, ln15, lnoff0;
};
__device__ __forceinline__ Addr256 addr256() {
  Addr256 a;
  int tid = threadIdx.x;
  a.wave = tid >> 6; a.ln = tid & 63;
  a.wm = a.wave >> 2; a.wn = a.wave & 3;
  a.ln15 = a.ln & 15;
  a.lnoff0 = a.ln15 * 128 + (((a.ln >> 4) * 16) ^ ((a.ln15 & 7) << 4));
  return a;
}
template <int LD>
__device__ __forceinline__ int srcOff256(int wave, int ln) {
  return (wave * 16 + (ln >> 3)) * LD + (((ln & 7) * 8) ^ ((ln >> 3) << 3));
}

// ------------------------------------------- GEMM: Q,K projection (ld=1024)
__global__ __launch_bounds__(512) void gemm_qk256(const ushort* __restrict__ xbf,
                                                  const ushort* __restrict__ WtT,
                                                  const float* __restrict__ bcat,
                                                  ushort* __restrict__ QK) {
  __shared__ __align__(16) char lds[131072];
  int tm = blockIdx.x, tn = blockIdx.y;            // (32, 16)
  Addr256 a = addr256();
  int srcOff = srcOff256<1024>(a.wave, a.ln);
  const ushort* Ap = xbf + (size_t)tm * 256 * 1024;
  const ushort* Bp = WtT + (size_t)tn * 256 * 1024;
  floatx4 acc[8][4];
#pragma unroll
  for (int i = 0; i < 8; ++i)
#pragma unroll
    for (int j = 0; j < 4; ++j) acc[i][j] = (floatx4){0.f, 0.f, 0.f, 0.f};

  prologue256<1024, 1024>(Ap, Bp, lds, a.wave, srcOff, srcOff);
#pragma unroll 1
  for (int i = 0; i < 7; ++i)
    iter256<1024, 1024, false>(Ap, Bp, lds, 2 * i, a.wave, a.wm, a.wn, srcOff, srcOff, a.lnoff0, acc);
  iter256<1024, 1024, true>(Ap, Bp, lds, 14, a.wave, a.wm, a.wn, srcOff, srcOff, a.lnoff0, acc);

  // epilogue: bias + bf16 store; nj innermost -> 4 consecutive stores per line.
  int colb = a.ln15, rowq = (a.ln >> 4) * 4;
  int colbase = tn * 256 + a.wn * 64 + colb;
  float bias[4];
#pragma unroll
  for (int nj = 0; nj < 4; ++nj) bias[nj] = bcat[colbase + nj * 16];
#pragma unroll
  for (int mi = 0; mi < 8; ++mi) {
    int row = tm * 256 + a.wm * 128 + mi * 16 + rowq;
#pragma unroll
    for (int r = 0; r < 4; ++r) {
      ushort* qrow = QK + (size_t)(row + r) * NQK;
#pragma unroll
      for (int nj = 0; nj < 4; ++nj)
        qrow[colbase + nj * 16] = f2bf(acc[mi][nj][r] + bias[nj]);
    }
  }
}

// ------------------- FUSED: S = Q*K^T (causal, 144 blk) + V proj (256 blk)
// l < 144: S-tile, XCD-grouped: xcd=l&7 owns half of batch b=xcd>>1's
// triangle (t=(xcd&1)*18 + l>>3) -> Q/K panels stay in that XCD's L2.
// l >= 144: V-tile (v=l-144, tn=v&7 -> same B panel per XCD, tmv=v>>3).
__global__ __launch_bounds__(512) void gemm_sv(const ushort* __restrict__ QK,
                                               const ushort* __restrict__ xbf,
                                               const ushort* __restrict__ WtT,
                                               const float* __restrict__ bcat,
                                               float* __restrict__ S,
                                               ushort* __restrict__ Vt) {
  __shared__ __align__(16) char lds[131072];
  int l = blockIdx.x;
  Addr256 a = addr256();
  floatx4 acc[8][4];
#pragma unroll
  for (int i = 0; i < 8; ++i)
#pragma unroll
    for (int j = 0; j < 4; ++j) acc[i][j] = (floatx4){0.f, 0.f, 0.f, 0.f};

  if (l < 144) {
    // ---------------- S branch ----------------
    int xcd = l & 7, j = l >> 3;
    int b = xcd >> 1;
    int t = (xcd & 1) * 18 + j;                    // triangle index 0..35
    int tm = (int)((sqrtf(8.f * t + 1.f) - 1.f) * 0.5f);
    while ((tm + 1) * (tm + 2) / 2 <= t) ++tm;
    while (tm * (tm + 1) / 2 > t) --tm;
    int tn = t - tm * (tm + 1) / 2;
    int srcOff = srcOff256<NQK>(a.wave, a.ln);
    const ushort* Ap = QK + (size_t)b * T_ * NQK + (size_t)tm * 256 * NQK;         // Q rows
    const ushort* Bp = QK + (size_t)b * T_ * NQK + (size_t)tn * 256 * NQK + 2048;  // K rows
    prologue256<NQK, NQK>(Ap, Bp, lds, a.wave, srcOff, srcOff);
#pragma unroll 1
    for (int i = 0; i < 15; ++i)
      iter256<NQK, NQK, false>(Ap, Bp, lds, 2 * i, a.wave, a.wm, a.wn, srcOff, srcOff, a.lnoff0, acc);
    iter256<NQK, NQK, true>(Ap, Bp, lds, 30, a.wave, a.wm, a.wn, srcOff, srcOff, a.lnoff0, acc);

    float* Sb = S + (size_t)b * T_ * T_;
    int colb = a.ln15, rowq = (a.ln >> 4) * 4;
    int colbase = tn * 256 + a.wn * 64 + colb;
#pragma unroll
    for (int mi = 0; mi < 8; ++mi) {
      int row = tm * 256 + a.wm * 128 + mi * 16 + rowq;
#pragma unroll
      for (int r = 0; r < 4; ++r) {
        float* srow = Sb + (size_t)(row + r) * T_;
#pragma unroll
        for (int nj = 0; nj < 4; ++nj)
          srow[colbase + nj * 16] = acc[mi][nj][r] * SCALE;
      }
    }
  } else {
    // ---------------- V branch (256^2 core + LDS transpose) ----------------
    int v = l - 144;
    int tn = v & 7, tmv = v >> 3;                  // tn over HEAD/256, tmv over 8192/256
    int srcOff = srcOff256<1024>(a.wave, a.ln);
    const ushort* Ap = xbf + (size_t)tmv * 256 * 1024;
    const ushort* Bp = WtT + (size_t)(4096 + tn * 256) * 1024;
    prologue256<1024, 1024>(Ap, Bp, lds, a.wave, srcOff, srcOff);
#pragma unroll 1
    for (int i = 0; i < 7; ++i)
      iter256<1024, 1024, false>(Ap, Bp, lds, 2 * i, a.wave, a.wm, a.wn, srcOff, srcOff, a.lnoff0, acc);
    iter256<1024, 1024, true>(Ap, Bp, lds, 14, a.wave, a.wm, a.wn, srcOff, srcOff, a.lnoff0, acc);

    // write acc (bias + f2bf) into LDS transposed [h][s], 256x512B (=128KiB);
    // swizzle: phys = h*512 + ((s*2) ^ ((h&31)<<4))  (write conflict-free).
    // K-loop's final BARX ordered all LDS reads before this overwrite.
#pragma unroll
    for (int nj = 0; nj < 4; ++nj) {
      int h = a.wn * 64 + nj * 16 + a.ln15;
      float bv = bcat[4096 + tn * 256 + h];
      int xr = (h & 31) << 4;
#pragma unroll
      for (int mi = 0; mi < 8; ++mi) {
        int s0 = a.wm * 128 + mi * 16 + (a.ln >> 4) * 4;
        ushort4 o4;
        o4.x = f2bf(acc[mi][nj][0] + bv);
        o4.y = f2bf(acc[mi][nj][1] + bv);
        o4.z = f2bf(acc[mi][nj][2] + bv);
        o4.w = f2bf(acc[mi][nj][3] + bv);
        *(ushort4*)(lds + h * 512 + ((s0 * 2) ^ xr)) = o4;
      }
    }
    __syncthreads();
    // read rows of [h][s], store coalesced into Vt[b][h_g][s_g]
    int tid = threadIdx.x;
    int b = tmv >> 3, sbase = (tmv & 7) * 256;
    int hr = tid >> 5;                 // 0..15
    int sc16 = tid & 31;               // 16B slot within 512B row
#pragma unroll
    for (int it = 0; it < 16; ++it) {
      int h = it * 16 + hr;
      ushortx8 vv = *(const ushortx8*)(lds + h * 512 + ((sc16 * 16) ^ ((h & 31) << 4)));
      *(ushortx8*)(Vt + ((size_t)b * T_ + tn * 256 + h) * T_ + sbase + sc16 * 8) = vv;
    }
  }
}

// ------------------------------------------------ GEMM: O = P*V (causal, split-K)
// grid (8 tn, 4 b, 12 slot). tm>=4 rows are split into two K-chunks that
// atomicAdd into O (pre-zeroed by softmax; exactly 2 fp32 contributors ->
// commutative -> bitwise deterministic). Slots ordered longest-first.
__global__ __launch_bounds__(512) void gemm_o256(const ushort* __restrict__ P,
                                                 const ushort* __restrict__ Vt,
                                                 float* __restrict__ O) {
  static constexpr int SLOT_TM[12] = {7, 7, 3, 6, 6, 5, 5, 2, 4, 4, 1, 0};
  static constexpr int SLOT_I0[12] = {0, 8, 0, 0, 7, 0, 6, 0, 0, 5, 0, 0};
  static constexpr int SLOT_NI[12] = {8, 8, 8, 7, 7, 6, 6, 6, 5, 5, 4, 2};
  int tn = blockIdx.x, b = blockIdx.y, slot = blockIdx.z;
  int tm = SLOT_TM[slot], i0 = SLOT_I0[slot], ni = SLOT_NI[slot];
  __shared__ __align__(16) char lds[131072];
  Addr256 a = addr256();
  int srcOff = srcOff256<T_>(a.wave, a.ln);
  const ushort* Ap = P + (size_t)b * T_ * T_ + (size_t)tm * 256 * T_ + i0 * 128;
  const ushort* Bp = Vt + (size_t)b * T_ * T_ + (size_t)tn * 256 * T_ + i0 * 128;
  floatx4 acc[8][4];
#pragma unroll
  for (int i = 0; i < 8; ++i)
#pragma unroll
    for (int j = 0; j < 4; ++j) acc[i][j] = (floatx4){0.f, 0.f, 0.f, 0.f};

  prologue256<T_, T_>(Ap, Bp, lds, a.wave, srcOff, srcOff);
#pragma unroll 1
  for (int i = 0; i < ni - 1; ++i)
    iter256<T_, T_, false>(Ap, Bp, lds, 2 * i, a.wave, a.wm, a.wn, srcOff, srcOff, a.lnoff0, acc);
  iter256<T_, T_, true>(Ap, Bp, lds, 2 * (ni - 1), a.wave, a.wm, a.wn, srcOff, srcOff, a.lnoff0, acc);

  float* Ob = O + (size_t)b * T_ * T_;
  int colb = a.ln15, rowq = (a.ln >> 4) * 4;
  int colbase = tn * 256 + a.wn * 64 + colb;
  if (tm >= 4) {
#pragma unroll
    for (int mi = 0; mi < 8; ++mi) {
      int row = tm * 256 + a.wm * 128 + mi * 16 + rowq;
#pragma unroll
      for (int r = 0; r < 4; ++r) {
        float* orow = Ob + (size_t)(row + r) * T_;
#pragma unroll
        for (int nj = 0; nj < 4; ++nj)
          atomicAdd(&orow[colbase + nj * 16], acc[mi][nj][r]);
      }
    }
  } else {
#pragma unroll
    for (int mi = 0; mi < 8; ++mi) {
      int row = tm * 256 + a.wm * 128 + mi * 16 + rowq;
#pragma unroll
      for (int r = 0; r < 4; ++r) {
        float* orow = Ob + (size_t)(row + r) * T_;
#pragma unroll
        for (int nj = 0; nj < 4; ++nj)
          orow[colbase + nj * 16] = acc[mi][nj][r];
      }
    }
  }
}

// ------------------------------------------------------------ causal softmax
// Also zeroes its own S/O row (same memory) for t>=1024 after reading it,
// so gemm_o256's split-K atomicAdd lands on zeroed accumulators.
__global__ __launch_bounds__(256) void softmax_causal(float* __restrict__ S,
                                                      ushort* __restrict__ P) {
  int t = blockIdx.x, b = blockIdx.y;
  int tid = threadIdx.x;
  float* srow = S + ((size_t)b * T_ + t) * T_;
  ushort* prow = P + ((size_t)b * T_ + t) * T_;
  int band = ((t >> 8) + 1) << 8;    // round_up(t+1, 256) == gemm_o256 k_end
  float xv[8];
  float m = -INFINITY;
#pragma unroll
  for (int c = 0; c < 2; ++c) {
    int s0 = c * 1024 + tid * 4;
    float* xs = xv + c * 4;
    if (s0 < band) {
      float4 v = *(const float4*)(srow + s0);
      xs[0] = (s0 + 0 <= t) ? v.x : -INFINITY;  // scale applied in gemm_s
      xs[1] = (s0 + 1 <= t) ? v.y : -INFINITY;
      xs[2] = (s0 + 2 <= t) ? v.z : -INFINITY;
      xs[3] = (s0 + 3 <= t) ? v.w : -INFINITY;
      m = fmaxf(fmaxf(fmaxf(xs[0], xs[1]), fmaxf(xs[2], xs[3])), m);
    } else {
      xs[0] = xs[1] = xs[2] = xs[3] = -INFINITY;
    }
  }
  __shared__ float sm4[4];
  int wid = tid >> 6, ln = tid & 63;
#pragma unroll
  for (int o = 32; o; o >>= 1) m = fmaxf(m, __shfl_xor(m, o));
  if (ln == 0) sm4[wid] = m;
  __syncthreads();
  m = fmaxf(fmaxf(sm4[0], sm4[1]), fmaxf(sm4[2], sm4[3]));
  __syncthreads();
  float sum = 0.f;
#pragma unroll
  for (int k = 0; k < 8; ++k) { xv[k] = __expf(xv[k] - m); sum += xv[k]; }
#pragma unroll
  for (int o = 32; o; o >>= 1) sum += __shfl_xor(sum, o);
  if (ln == 0) sm4[wid] = sum;
  __syncthreads();
  sum = sm4[0] + sm4[1] + sm4[2] + sm4[3];
  float inv = 1.0f / sum;
#pragma unroll
  for (int c = 0; c < 2; ++c) {
    int s0 = c * 1024 + tid * 4;
    if (s0 < band) {
      ushort4 o4;
      o4.x = f2bf(xv[c * 4 + 0] * inv);
      o4.y = f2bf(xv[c * 4 + 1] * inv);
      o4.z = f2bf(xv[c * 4 + 2] * inv);
      o4.w = f2bf(xv[c * 4 + 3] * inv);
      *(ushort4*)(prow + s0) = o4;
    }
  }
  if (t >= 1024) {                   // zero own O row for split-K atomics
    float4 z = {0.f, 0.f, 0.f, 0.f};
    ((float4*)srow)[tid] = z;
    ((float4*)srow)[256 + tid] = z;
  }
}

// ---------------------------------------------------------------- launcher
extern "C" void kernel_launch(void* const* d_in, const int* in_sizes, int n_in,
                              void* d_out, int out_size, void* d_ws, size_t ws_size,
                              hipStream_t stream) {
  (void)in_sizes; (void)n_in; (void)out_size; (void)ws_size;
  const float* x  = (const float*)d_in[0];
  const float* Wq = (const float*)d_in[1];
  const float* bq = (const float*)d_in[2];
  const float* Wk = (const float*)d_in[3];
  const float* bk = (const float*)d_in[4];
  const float* Wv = (const float*)d_in[5];
  const float* bv = (const float*)d_in[6];

  char* ws = (char*)d_ws;
  ushort* xbf  = (ushort*)(ws + 0);           // 16,777,216 B
  ushort* WtT  = (ushort*)(ws + 16777216);    // 12,582,912 B
  float*  bcat = (float*) (ws + 29360128);    //     24,576 B
  ushort* QK   = (ushort*)(ws + 29384704);    // 67,108,864 B  [8192][4096]
  ushort* P    = (ushort*)(ws + 96493568);    // 33,554,432 B
  ushort* Vt   = (ushort*)(ws + 130048000);   // 33,554,432 B  (end ~156 MiB)

  float* S = (float*)d_out;   // S scratch lives in d_out, later overwritten by O
  float* O = (float*)d_out;

  prep_kernel    <<<14360, 256, 0, stream>>>(x, xbf, Wq, Wk, Wv, WtT, bq, bk, bv, bcat);
  gemm_qk256     <<<dim3(32, 16), 512, 0, stream>>>(xbf, WtT, bcat, QK);
  gemm_sv        <<<400, 512, 0, stream>>>(QK, xbf, WtT, bcat, S, Vt);
  softmax_causal <<<dim3(2048, 4), 256, 0, stream>>>(S, P);
  gemm_o256      <<<dim3(8, 4, 12), 512, 0, stream>>>(P, Vt, O);
}